// Round 1
// baseline (234.616 us; speedup 1.0000x reference)
//
#include <hip/hip_runtime.h>

// Problem shape (fixed by the reference): B=32, C=64, H=128, W=128, N_KNOTS=65.
// x layout is (B, C, H, W) row-major -> channel changes every H*W = 16384 elements.
// Each thread processes one float4 (4 contiguous elements). A 256-thread block
// covers 1024 contiguous elements => entire block is within ONE channel
// (16384 % 1024 == 0), so we stage that channel's 65 coefficients in LDS.

__global__ __launch_bounds__(256) void quad_spline_kernel(
    const float4* __restrict__ x,
    const float*  __restrict__ coeffs,
    const float*  __restrict__ grid_p,
    const int*    __restrict__ zki,
    const int*    __restrict__ size_p,
    float4*       __restrict__ out)
{
    __shared__ float lds_c[65];

    const int gid = blockIdx.x * 256 + threadIdx.x;   // float4 index
    const int c   = (gid >> 12) & 63;                 // 4096 float4 per channel

    const float g    = grid_p[0];
    const int   size = size_p[0];
    const int   half = size >> 1;                     // 32
    const int   base = zki[c] - half;                 // channel's table base = c*size

    // stage this channel's 65-entry table into LDS
    if (threadIdx.x < 65) lds_c[threadIdx.x] = coeffs[base + threadIdx.x];
    __syncthreads();

    const float lo = -g * (float)half;                // -4.0
    const float hi =  g * (float)(half - 2);          //  3.75

    float4 xv = x[gid];
    float4 r;
    float* xp = &xv.x;
    float* rp = &r.x;

#pragma unroll
    for (int k = 0; k < 4; ++k) {
        float xx = xp[k];
        float xc = fminf(fmaxf(xx, lo), hi);          // clamp (for index only)
        float fl = floorf(xc / g);                    // floored_x; g=0.125 pow2 -> exact
        int   idx = half + (int)fl;                   // local knot index in [0, 62]
        float s  = (xx - fl * g) / g;                 // fractional pos, UNCLAMPED x
        float f1 = (s - 1.0f) * (s - 1.0f) * 0.5f;
        float f2 = (-2.0f * s * s + 2.0f * s + 1.0f) * 0.5f;
        float f3 = s * s * 0.5f;
        float c0 = lds_c[idx];
        float c1 = lds_c[idx + 1];
        float c2 = lds_c[idx + 2];
        rp[k] = c2 * f3 + c1 * f2 + c0 * f1;
    }
    out[gid] = r;
}

extern "C" void kernel_launch(void* const* d_in, const int* in_sizes, int n_in,
                              void* d_out, int out_size, void* d_ws, size_t ws_size,
                              hipStream_t stream) {
    const float4* x      = (const float4*)d_in[0];
    const float*  coeffs = (const float*)d_in[1];
    const float*  grid_p = (const float*)d_in[2];
    const int*    zki    = (const int*)d_in[3];
    const int*    size_p = (const int*)d_in[4];
    float4*       out    = (float4*)d_out;

    const int n4     = in_sizes[0] / 4;      // 2,097,152 float4
    const int blocks = n4 / 256;             // 8192 blocks

    quad_spline_kernel<<<blocks, 256, 0, stream>>>(x, coeffs, grid_p, zki, size_p, out);
}

// Round 3
// 232.340 us; speedup vs baseline: 1.0098x; 1.0098x over previous
//
#include <hip/hip_runtime.h>

// B=32, C=64, H=128, W=128, N_KNOTS=65. x is (B,C,H,W) row-major.
// One thread per 4 contiguous floats. Per-(b,c) slice = 16384 elems = 4096
// vec4, and a 256-thread block covers 1024 contiguous elements; 16384 % 1024
// == 0 => whole block sits in ONE channel. Stage that channel's 65
// coefficients in LDS; gather locally. Multiply by inv_g (g = 2^-3, exact)
// instead of dividing. Native clang vectors so nontemporal builtins accept
// the pointers (HIP_vector_type float4 is rejected).

typedef float vfloat4 __attribute__((ext_vector_type(4)));

__device__ __forceinline__ float spline_eval(float xx, const float* lds_c,
                                             float g, float inv_g,
                                             float lo, float hi, int half) {
    float xc  = fminf(fmaxf(xx, lo), hi);
    float fl  = floorf(xc * inv_g);          // exact for g = 2^-3
    int   idx = half + (int)fl;              // in [0, 62]
    float s   = (xx - fl * g) * inv_g;       // UNCLAMPED x, per reference
    float f1  = (s - 1.0f) * (s - 1.0f) * 0.5f;
    float f2  = (-2.0f * s * s + 2.0f * s + 1.0f) * 0.5f;
    float f3  = s * s * 0.5f;
    float c0  = lds_c[idx];
    float c1  = lds_c[idx + 1];
    float c2  = lds_c[idx + 2];
    return c2 * f3 + c1 * f2 + c0 * f1;
}

__global__ __launch_bounds__(256) void quad_spline_kernel(
    const vfloat4* __restrict__ x,
    const float*   __restrict__ coeffs,
    const float*   __restrict__ grid_p,
    const int*     __restrict__ zki,
    const int*     __restrict__ size_p,
    vfloat4*       __restrict__ out)
{
    __shared__ float lds_c[65];

    const int gid = blockIdx.x * 256 + threadIdx.x;  // vec4 index
    const int c   = (gid >> 12) & 63;                // 4096 vec4 per (b,c) slice

    const float g    = grid_p[0];
    const int   size = size_p[0];
    const int   half = size >> 1;                    // 32
    const int   base = zki[c] - half;                // = c * size

    if (threadIdx.x < 65) lds_c[threadIdx.x] = coeffs[base + threadIdx.x];
    __syncthreads();

    const float inv_g = 1.0f / g;                    // exact (g = 0.125)
    const float lo    = -g * (float)half;            // -4.0
    const float hi    =  g * (float)(half - 2);      //  3.75

    vfloat4 xv = __builtin_nontemporal_load(&x[gid]);
    vfloat4 r;
    r.x = spline_eval(xv.x, lds_c, g, inv_g, lo, hi, half);
    r.y = spline_eval(xv.y, lds_c, g, inv_g, lo, hi, half);
    r.z = spline_eval(xv.z, lds_c, g, inv_g, lo, hi, half);
    r.w = spline_eval(xv.w, lds_c, g, inv_g, lo, hi, half);
    __builtin_nontemporal_store(r, &out[gid]);
}

extern "C" void kernel_launch(void* const* d_in, const int* in_sizes, int n_in,
                              void* d_out, int out_size, void* d_ws, size_t ws_size,
                              hipStream_t stream) {
    const vfloat4* x      = (const vfloat4*)d_in[0];
    const float*   coeffs = (const float*)d_in[1];
    const float*   grid_p = (const float*)d_in[2];
    const int*     zki    = (const int*)d_in[3];
    const int*     size_p = (const int*)d_in[4];
    vfloat4*       out    = (vfloat4*)d_out;

    const int n4     = in_sizes[0] / 4;   // 2,097,152 vec4
    const int blocks = n4 / 256;          // 8192 blocks

    quad_spline_kernel<<<blocks, 256, 0, stream>>>(x, coeffs, grid_p, zki, size_p, out);
}

// Round 4
// 232.200 us; speedup vs baseline: 1.0104x; 1.0006x over previous
//
#include <hip/hip_runtime.h>

// B=32, C=64, H=128, W=128, N_KNOTS=65. x is (B,C,H,W) row-major.
// One thread per 4 contiguous floats; 256-thread block covers 1024 contiguous
// elements; 16384 % 1024 == 0 => whole block sits in ONE channel. Stage that
// channel's 65 coefficients in LDS (scalar b32 gathers: 64 lanes over 32
// banks = 2-way avg, which is free per m136).
//
// Math rewrite (vs reference, same values to ~1 ulp; threshold 180):
//   t  = x * inv_g                  (exact: g = 2^-3)
//   fl = clamp(floor(t), -32, 30)   (== floor(clamp(x)/g), shown equal)
//   s  = t - fl                     (== (x - fl*g)/g)
//   f1+f2+f3 == 1  =>  out = c1 + u^2*(c0-c1)/2 + s^2*(c2-c1)/2,  u = s-1

typedef float vfloat4 __attribute__((ext_vector_type(4)));

__device__ __forceinline__ float spline_eval(float xx, const float* lds_c,
                                             float inv_g, float flo, float fhi,
                                             int half) {
    float t   = xx * inv_g;
    float fl  = fminf(fmaxf(floorf(t), flo), fhi);   // [-32, 30]
    int   idx = half + (int)fl;                      // [0, 62]
    float s   = t - fl;                              // shift1 (unclamped x)
    float u   = s - 1.0f;
    float c0  = lds_c[idx];
    float c1  = lds_c[idx + 1];
    float c2  = lds_c[idx + 2];
    float h0  = 0.5f * (c0 - c1);
    float h2  = 0.5f * (c2 - c1);
    return fmaf(u * u, h0, fmaf(s * s, h2, c1));
}

__global__ __launch_bounds__(256) void quad_spline_kernel(
    const vfloat4* __restrict__ x,
    const float*   __restrict__ coeffs,
    const float*   __restrict__ grid_p,
    const int*     __restrict__ zki,
    const int*     __restrict__ size_p,
    vfloat4*       __restrict__ out)
{
    __shared__ float lds_c[65];

    const int gid = blockIdx.x * 256 + threadIdx.x;  // vec4 index
    const int c   = (gid >> 12) & 63;                // 4096 vec4 per (b,c) slice

    const float g    = grid_p[0];
    const int   size = size_p[0];
    const int   half = size >> 1;                    // 32
    const int   base = zki[c] - half;                // = c * size

    if (threadIdx.x < 65) lds_c[threadIdx.x] = coeffs[base + threadIdx.x];
    __syncthreads();

    const float inv_g = 1.0f / g;                    // exact (g = 0.125)
    const float flo   = -(float)half;                // -32
    const float fhi   =  (float)(half - 2);          //  30

    vfloat4 xv = __builtin_nontemporal_load(&x[gid]);
    vfloat4 r;
    r.x = spline_eval(xv.x, lds_c, inv_g, flo, fhi, half);
    r.y = spline_eval(xv.y, lds_c, inv_g, flo, fhi, half);
    r.z = spline_eval(xv.z, lds_c, inv_g, flo, fhi, half);
    r.w = spline_eval(xv.w, lds_c, inv_g, flo, fhi, half);
    __builtin_nontemporal_store(r, &out[gid]);
}

extern "C" void kernel_launch(void* const* d_in, const int* in_sizes, int n_in,
                              void* d_out, int out_size, void* d_ws, size_t ws_size,
                              hipStream_t stream) {
    const vfloat4* x      = (const vfloat4*)d_in[0];
    const float*   coeffs = (const float*)d_in[1];
    const float*   grid_p = (const float*)d_in[2];
    const int*     zki    = (const int*)d_in[3];
    const int*     size_p = (const int*)d_in[4];
    vfloat4*       out    = (vfloat4*)d_out;

    const int n4     = in_sizes[0] / 4;   // 2,097,152 vec4
    const int blocks = n4 / 256;          // 8192 blocks

    quad_spline_kernel<<<blocks, 256, 0, stream>>>(x, coeffs, grid_p, zki, size_p, out);
}